// Round 4
// baseline (88.781 us; speedup 1.0000x reference)
//
#include <hip/hip_runtime.h>

#define Bn 32
#define Cn 256
#define HWn 3136          // 56*56
#define HW4 784           // HWn/4 = 64*12 + 16
#define NTHREADS 256

typedef float f4 __attribute__((ext_vector_type(4)));

__device__ __forceinline__ float dot4(f4 a, f4 b) {
  return a.x * b.x + a.y * b.y + a.z * b.z + a.w * b.w;
}

// ---------------------------------------------------------------------------
// K1: ONE WAVE per (b,c) plane; 2048 blocks x 256 thr = 8192 waves.
// Each lane streams 12 f4 per input (x, cg, dg), unrolled x4 so 12 loads are
// in flight per stage. No LDS, no __syncthreads -- waves fully decoupled,
// continuous memory issue. cg/dg single-use -> nontemporal (preserve L3 for x).
// ---------------------------------------------------------------------------
__global__ __launch_bounds__(NTHREADS) void importance_kernel(
    const float* __restrict__ x, const float* __restrict__ cg,
    const float* __restrict__ dg, float* __restrict__ cim,
    float* __restrict__ dimv) {
  const int lane = threadIdx.x & 63;
  const int bc = (blockIdx.x << 2) | (threadIdx.x >> 6);  // plane id 0..8191
  const size_t base = (size_t)bc * HWn;
  const f4* __restrict__ xp = (const f4*)(x + base);
  const f4* __restrict__ cp = (const f4*)(cg + base);
  const f4* __restrict__ dp = (const f4*)(dg + base);

  float accC = 0.f, accD = 0.f;
#pragma unroll
  for (int i = 0; i < 12; i += 4) {
    f4 x0 = xp[lane + 64 * (i + 0)];
    f4 x1 = xp[lane + 64 * (i + 1)];
    f4 x2 = xp[lane + 64 * (i + 2)];
    f4 x3 = xp[lane + 64 * (i + 3)];
    f4 c0 = __builtin_nontemporal_load(cp + lane + 64 * (i + 0));
    f4 c1 = __builtin_nontemporal_load(cp + lane + 64 * (i + 1));
    f4 c2 = __builtin_nontemporal_load(cp + lane + 64 * (i + 2));
    f4 c3 = __builtin_nontemporal_load(cp + lane + 64 * (i + 3));
    f4 d0 = __builtin_nontemporal_load(dp + lane + 64 * (i + 0));
    f4 d1 = __builtin_nontemporal_load(dp + lane + 64 * (i + 1));
    f4 d2 = __builtin_nontemporal_load(dp + lane + 64 * (i + 2));
    f4 d3 = __builtin_nontemporal_load(dp + lane + 64 * (i + 3));
    accC += dot4(x0, c0) + dot4(x1, c1) + dot4(x2, c2) + dot4(x3, c3);
    accD += dot4(x0, d0) + dot4(x1, d1) + dot4(x2, d2) + dot4(x3, d3);
  }
  // tail: f4 indices 768..783, lanes 0..15
  if (lane < 16) {
    f4 xt = xp[768 + lane];
    f4 ct = __builtin_nontemporal_load(cp + 768 + lane);
    f4 dt = __builtin_nontemporal_load(dp + 768 + lane);
    accC += dot4(xt, ct);
    accD += dot4(xt, dt);
  }

  // wave-local reduce (64 lanes)
  for (int off = 32; off; off >>= 1) {
    accC += __shfl_down(accC, off);
    accD += __shfl_down(accD, off);
  }
  if (lane == 0) {
    cim[bc] = accC * (1.0f / HWn);
    dimv[bc] = accD * (1.0f / HWn);
  }
}

// ---------------------------------------------------------------------------
// K2: per-sample quantile thresholds (rank selection over 256 channels) and
// mask generation: m1 = cs&ds, m2 = (!cs)&ds, mdi = !ds
// quantile(0.5): pos = 127.5 -> 0.5*(s127+s128); quantile(0.8): pos=204 -> s204
// ---------------------------------------------------------------------------
__global__ __launch_bounds__(NTHREADS) void quantile_mask_kernel(
    const float* __restrict__ cim, const float* __restrict__ dimv,
    float* __restrict__ m1, float* __restrict__ m2, float* __restrict__ mdi) {
  const int b = blockIdx.x;
  const int c = threadIdx.x;
  __shared__ float sc[Cn], sd[Cn];
  __shared__ float q127, q128, q204;
  const float v = cim[b * Cn + c];
  const float w = dimv[b * Cn + c];
  sc[c] = v;
  sd[c] = w;
  __syncthreads();

  int cl = 0, ce = 0, dl = 0, de = 0;
  for (int j = 0; j < Cn; ++j) {
    float u = sc[j];
    cl += (u < v);
    ce += (u == v);
    float t = sd[j];
    dl += (t < w);
    de += (t == w);
  }
  if (cl <= 127 && 127 < cl + ce) q127 = v;
  if (cl <= 128 && 128 < cl + ce) q128 = v;
  if (dl <= 204 && 204 < dl + de) q204 = w;
  __syncthreads();

  const float cthr = 0.5f * (q127 + q128);
  const float dthr = q204;
  const bool cs = v > cthr;
  const bool ds = w > dthr;
  m1[b * Cn + c] = (cs && ds) ? 1.f : 0.f;
  m2[b * Cn + c] = (!cs && ds) ? 1.f : 0.f;
  mdi[b * Cn + c] = ds ? 0.f : 1.f;
}

// ---------------------------------------------------------------------------
// K3: out[b,c,:] = A*x[b,c,:] + B1*x[sb,c,:] + B2*x[db,c,:]
// x reads come mostly from L3; out never read back -> nontemporal stores.
// ---------------------------------------------------------------------------
__global__ __launch_bounds__(NTHREADS) void mix_kernel(
    const float* __restrict__ x, const float* __restrict__ ms,
    const int* __restrict__ same_idx, const int* __restrict__ diff_idx,
    const float* __restrict__ m1, const float* __restrict__ m2,
    const float* __restrict__ mdi, float* __restrict__ out) {
  const int bc = blockIdx.x;
  const int b = bc >> 8;
  const int c = bc & 255;
  const int sb = same_idx[b];
  const int db = diff_idx[b];
  const float s0 = ms[b * 2 + 0];
  const float s1 = ms[b * 2 + 1];

  const float A = mdi[bc] + s0 * m1[bc] + s1 * m2[bc];
  const float B1 = (1.f - s0) * m1[sb * Cn + c];
  const float B2 = (1.f - s1) * m2[db * Cn + c];

  const f4* __restrict__ xp = (const f4*)(x + (size_t)bc * HWn);
  const f4* __restrict__ xs = (const f4*)(x + ((size_t)sb * Cn + c) * HWn);
  const f4* __restrict__ xd = (const f4*)(x + ((size_t)db * Cn + c) * HWn);
  f4* __restrict__ op = (f4*)(out + (size_t)bc * HWn);

  const bool u1 = (B1 != 0.f);
  const bool u2 = (B2 != 0.f);
  const int t = threadIdx.x;

  f4 r0, r1, r2;
  {
    f4 xv0 = xp[t];
    f4 xv1 = xp[t + 256];
    f4 xv2 = xp[t + 512];
    r0 = A * xv0;
    r1 = A * xv1;
    r2 = A * xv2;
  }
  if (u1) {
    f4 s0v = xs[t];
    f4 s1v = xs[t + 256];
    f4 s2v = xs[t + 512];
    r0 += B1 * s0v;
    r1 += B1 * s1v;
    r2 += B1 * s2v;
  }
  if (u2) {
    f4 d0v = xd[t];
    f4 d1v = xd[t + 256];
    f4 d2v = xd[t + 512];
    r0 += B2 * d0v;
    r1 += B2 * d1v;
    r2 += B2 * d2v;
  }
  __builtin_nontemporal_store(r0, op + t);
  __builtin_nontemporal_store(r1, op + t + 256);
  __builtin_nontemporal_store(r2, op + t + 512);

  if (t < 16) {
    f4 xv3 = xp[768 + t];
    f4 r3 = A * xv3;
    if (u1) {
      f4 s3v = xs[768 + t];
      r3 += B1 * s3v;
    }
    if (u2) {
      f4 d3v = xd[768 + t];
      r3 += B2 * d3v;
    }
    __builtin_nontemporal_store(r3, op + 768 + t);
  }
}

extern "C" void kernel_launch(void* const* d_in, const int* in_sizes, int n_in,
                              void* d_out, int out_size, void* d_ws, size_t ws_size,
                              hipStream_t stream) {
  const float* x  = (const float*)d_in[0];
  const float* cg = (const float*)d_in[1];
  const float* dg = (const float*)d_in[2];
  const float* ms = (const float*)d_in[3];
  // d_in[4] = y, d_in[5] = domain (unused: index pickers precomputed)
  const int* same_idx = (const int*)d_in[6];
  const int* diff_idx = (const int*)d_in[7];
  float* out = (float*)d_out;

  float* ws = (float*)d_ws;
  float* cim  = ws;                // B*C
  float* dimv = ws + Bn * Cn;      // B*C
  float* m1   = ws + 2 * Bn * Cn;  // B*C
  float* m2   = ws + 3 * Bn * Cn;  // B*C
  float* mdi  = ws + 4 * Bn * Cn;  // B*C

  importance_kernel<<<(Bn * Cn) / 4, NTHREADS, 0, stream>>>(x, cg, dg, cim, dimv);
  quantile_mask_kernel<<<Bn, NTHREADS, 0, stream>>>(cim, dimv, m1, m2, mdi);
  mix_kernel<<<Bn * Cn, NTHREADS, 0, stream>>>(x, ms, same_idx, diff_idx, m1, m2, mdi, out);
}